// Round 4
// baseline (511.635 us; speedup 1.0000x reference)
//
#include <hip/hip_runtime.h>
#include <hip/hip_bf16.h>
#include <cstdint>

// Shapes
#define BB 4
#define TT 256
#define UB 64
#define AA 512
#define DD 640
#define HH 640
#define VV 1024

typedef __attribute__((ext_vector_type(8))) short short8;
typedef __attribute__((ext_vector_type(4))) float f32x4;

__device__ __forceinline__ unsigned short f2bf(float f) {
    unsigned u = __builtin_bit_cast(unsigned, f);
    u += 0x7fffu + ((u >> 16) & 1u);   // RNE
    return (unsigned short)(u >> 16);
}

__device__ __forceinline__ float fast_tanh(float x) {
    return 1.0f - 2.0f / (1.0f + __expf(2.0f * x));
}

// ---------------------------------------------------------------------------
// kprep: fused W_out pack (blocks 0..319) + enc/dec projections (320..519).
//
// Pack: W_out (640x1024 f32) -> bf16 in MFMA B-fragment order:
//   flat = (kb*64+nb)*512 + n'*32 + hi*8 + j  for W[kb*32+hi*8+j][nb*16+n']
// Proj: 64x64 tile fp32 GEMM, BK=16, 4x4 micro-tile.
// ---------------------------------------------------------------------------
__global__ __launch_bounds__(256) void kprep(
    const float* __restrict__ W_out, unsigned short* __restrict__ wp,
    const float* __restrict__ enc_in, const float* __restrict__ dec_in,
    const float* __restrict__ We, const float* __restrict__ be,
    const float* __restrict__ Wd, const float* __restrict__ bd,
    float* __restrict__ enc_out, float* __restrict__ dec_out) {
    __shared__ float smem[16][137];   // union: pack tile[32][64] fits in first rows
    const int bi  = blockIdx.x;
    const int tid = threadIdx.x;

    if (bi < 320) {
        // ---- pack ----
        float (*tile)[64] = reinterpret_cast<float (*)[64]>(&smem[0][0]);
        const int kb  = bi >> 4;
        const int nbg = bi & 15;
#pragma unroll
        for (int i = 0; i < 8; ++i) {
            int idx = tid + (i << 8);
            int r = idx >> 6, c = idx & 63;
            tile[r][c] = W_out[(size_t)(kb * 32 + r) * VV + nbg * 64 + c];
        }
        __syncthreads();
        const int hi  = tid & 3;
        const int np  = (tid >> 2) & 15;
        const int nbl = tid >> 6;
        __align__(16) unsigned short v[8];
#pragma unroll
        for (int j = 0; j < 8; ++j)
            v[j] = f2bf(tile[hi * 8 + j][nbl * 16 + np]);
        size_t off = (size_t)((kb * 64 + nbg * 4 + nbl) * 512 + np * 32 + hi * 8);
        *reinterpret_cast<uint4*>(wp + off) = *reinterpret_cast<const uint4*>(v);
        return;
    }

    // ---- projections ----
    float (*As)[68] = reinterpret_cast<float (*)[68]>(&smem[0][0]);
    __shared__ float Bs[16][68];
    const int bj = bi - 320;
    const float *A, *W, *bias;
    float* C;
    int K, bm, bn;
    if (bj < 160) { A = enc_in; W = We; bias = be; C = enc_out; K = AA; bm = bj / 10; bn = bj - bm * 10; }
    else { int bq = bj - 160; A = dec_in; W = Wd; bias = bd; C = dec_out; K = DD; bm = bq / 10; bn = bq - bm * 10; }
    const int row0 = bm * 64, n0 = bn * 64;
    const int tm = tid & 15, tn = tid >> 4;
    const int am = tid >> 2, akq = tid & 3;        // A-stage: 4 lanes x 16B per row
    const int bk = tid >> 4, bn4 = (tid & 15) * 4; // B-stage: 256B per W row

    float acc[4][4] = {};
    float4 a4 = *reinterpret_cast<const float4*>(A + (size_t)(row0 + am) * K + akq * 4);
    float4 b4 = *reinterpret_cast<const float4*>(W + (size_t)bk * HH + n0 + bn4);

    for (int k0 = 0; k0 < K; k0 += 16) {
        As[akq * 4 + 0][am] = a4.x;
        As[akq * 4 + 1][am] = a4.y;
        As[akq * 4 + 2][am] = a4.z;
        As[akq * 4 + 3][am] = a4.w;
        *reinterpret_cast<float4*>(&Bs[bk][bn4]) = b4;
        __syncthreads();
        if (k0 + 16 < K) {
            a4 = *reinterpret_cast<const float4*>(A + (size_t)(row0 + am) * K + k0 + 16 + akq * 4);
            b4 = *reinterpret_cast<const float4*>(W + (size_t)(k0 + 16 + bk) * HH + n0 + bn4);
        }
#pragma unroll
        for (int kk = 0; kk < 16; ++kk) {
            float4 av = *reinterpret_cast<const float4*>(&As[kk][tm * 4]);
            float4 bv = *reinterpret_cast<const float4*>(&Bs[kk][tn * 4]);
            float a_[4] = {av.x, av.y, av.z, av.w};
            float b_[4] = {bv.x, bv.y, bv.z, bv.w};
#pragma unroll
            for (int i = 0; i < 4; ++i)
#pragma unroll
                for (int j = 0; j < 4; ++j)
                    acc[i][j] = fmaf(a_[i], b_[j], acc[i][j]);
        }
        __syncthreads();
    }
    float bv0 = bias[n0 + tn * 4 + 0], bv1 = bias[n0 + tn * 4 + 1];
    float bv2 = bias[n0 + tn * 4 + 2], bv3 = bias[n0 + tn * 4 + 3];
#pragma unroll
    for (int i = 0; i < 4; ++i) {
        float4 o = {acc[i][0] + bv0, acc[i][1] + bv1, acc[i][2] + bv2, acc[i][3] + bv3};
        *reinterpret_cast<float4*>(C + (size_t)(row0 + tm * 4 + i) * HH + n0 + tn * 4) = o;
    }
}

// ---------------------------------------------------------------------------
// Main fused kernel. One block per (b,t): 64 u-rows x 1024 vocab.
// 1024 threads = 16 waves = 2 rowgroups x 8 colgroups; wave = 32r x 128c,
// acc = 2x8 frags = 64 VGPRs/thread -> 4 waves/SIMD resident.
// z tile bf16 [64][640] in LDS, XOR swizzle byte^=((row&7)<<4).
// ---------------------------------------------------------------------------
__global__ __launch_bounds__(1024) void kmain(
    const float* __restrict__ encp, const float* __restrict__ decp,
    const unsigned short* __restrict__ wp, const float* __restrict__ bo,
    float* __restrict__ out) {
    __shared__ __align__(16) unsigned char zb[UB * 1280];  // 80 KiB
    __shared__ __align__(16) float red1[UB][8];
    __shared__ __align__(16) float red2[UB][8];
    const int bt   = blockIdx.x;      // b*256 + t
    const int b    = bt >> 8;
    const int tid  = threadIdx.x;
    const int lane = tid & 63;
    const int wv   = tid >> 6;        // 0..15
    const int cg   = wv & 7;          // colgroup 0..7
    const int rg_g = wv >> 3;         // rowgroup 0..1
    const int lo   = lane & 15;
    const int hi   = lane >> 4;
    const float* encr = encp + (size_t)bt * HH;
    const float* decr = decp + (size_t)b * UB * HH;

    // ---- phase 1: z = tanh(enc + dec) -> bf16 LDS (swizzled) ----
#pragma unroll
    for (int i = 0; i < 5; ++i) {
        int c  = tid + (i << 10);     // 0..5119 chunks of 8
        int u  = c / 80;
        int h0 = (c - u * 80) * 8;
        const float4* dp = reinterpret_cast<const float4*>(decr + (size_t)u * HH + h0);
        const float4* ep = reinterpret_cast<const float4*>(encr + h0);
        float4 d0 = dp[0], d1 = dp[1];
        float4 e0 = ep[0], e1 = ep[1];
        __align__(16) unsigned short zs[8];
        zs[0] = f2bf(fast_tanh(e0.x + d0.x));
        zs[1] = f2bf(fast_tanh(e0.y + d0.y));
        zs[2] = f2bf(fast_tanh(e0.z + d0.z));
        zs[3] = f2bf(fast_tanh(e0.w + d0.w));
        zs[4] = f2bf(fast_tanh(e1.x + d1.x));
        zs[5] = f2bf(fast_tanh(e1.y + d1.y));
        zs[6] = f2bf(fast_tanh(e1.z + d1.z));
        zs[7] = f2bf(fast_tanh(e1.w + d1.w));
        unsigned addr = (unsigned)(u * 1280 + h0 * 2) ^ ((unsigned)(u & 7) << 4);
        *reinterpret_cast<uint4*>(zb + addr) = *reinterpret_cast<const uint4*>(zs);
    }
    __syncthreads();

    // ---- phase 2: GEMM (64x640)@(640x1024), wave slice 32x128 ----
    f32x4 acc[2][8];
#pragma unroll
    for (int mf = 0; mf < 2; ++mf)
#pragma unroll
        for (int nf = 0; nf < 8; ++nf)
            acc[mf][nf] = (f32x4){0.f, 0.f, 0.f, 0.f};
    const int nb0 = cg * 8;
    const int r0  = rg_g * 32;
#pragma unroll 4
    for (int kb = 0; kb < 20; ++kb) {
        short8 af[2];
#pragma unroll
        for (int mf = 0; mf < 2; ++mf) {
            int row = r0 + mf * 16 + lo;
            unsigned addr = (unsigned)(row * 1280 + kb * 64 + hi * 16) ^
                            ((unsigned)(row & 7) << 4);
            af[mf] = *reinterpret_cast<const short8*>(zb + addr);
        }
#pragma unroll
        for (int nf = 0; nf < 8; ++nf) {
            const unsigned short* p =
                wp + (size_t)((kb * 64 + nb0 + nf) * 512 + lo * 32 + hi * 8);
            short8 bf = *reinterpret_cast<const short8*>(p);
#pragma unroll
            for (int mf = 0; mf < 2; ++mf)
                acc[mf][nf] = __builtin_amdgcn_mfma_f32_16x16x32_bf16(
                    af[mf], bf, acc[mf][nf], 0, 0, 0);
        }
    }

    // ---- phase 3: +bias, fused log-softmax, store ----
    const int n0 = cg * 128;
#pragma unroll
    for (int nf = 0; nf < 8; ++nf) {
        float bbv = bo[n0 + nf * 16 + lo];
#pragma unroll
        for (int mf = 0; mf < 2; ++mf) {
            acc[mf][nf][0] += bbv;
            acc[mf][nf][1] += bbv;
            acc[mf][nf][2] += bbv;
            acc[mf][nf][3] += bbv;
        }
    }

    // row max over V: in-lane nf, 16-lane shfl, cross-wave via LDS
#pragma unroll
    for (int mf = 0; mf < 2; ++mf)
#pragma unroll
        for (int rg = 0; rg < 4; ++rg) {
            float v = acc[mf][0][rg];
#pragma unroll
            for (int nf = 1; nf < 8; ++nf) v = fmaxf(v, acc[mf][nf][rg]);
            v = fmaxf(v, __shfl_xor(v, 1));
            v = fmaxf(v, __shfl_xor(v, 2));
            v = fmaxf(v, __shfl_xor(v, 4));
            v = fmaxf(v, __shfl_xor(v, 8));
            if (lo == 0) red1[r0 + mf * 16 + hi * 4 + rg][cg] = v;
        }
    __syncthreads();
    float rmax[2][4];
#pragma unroll
    for (int mf = 0; mf < 2; ++mf)
#pragma unroll
        for (int rg = 0; rg < 4; ++rg) {
            int row = r0 + mf * 16 + hi * 4 + rg;
            const float4* r4 = reinterpret_cast<const float4*>(&red1[row][0]);
            float4 x = r4[0], y = r4[1];
            rmax[mf][rg] = fmaxf(fmaxf(fmaxf(x.x, x.y), fmaxf(x.z, x.w)),
                                 fmaxf(fmaxf(y.x, y.y), fmaxf(y.z, y.w)));
        }
#pragma unroll
    for (int mf = 0; mf < 2; ++mf)
#pragma unroll
        for (int rg = 0; rg < 4; ++rg) {
            float s = 0.f;
#pragma unroll
            for (int nf = 0; nf < 8; ++nf)
                s += __expf(acc[mf][nf][rg] - rmax[mf][rg]);
            s += __shfl_xor(s, 1);
            s += __shfl_xor(s, 2);
            s += __shfl_xor(s, 4);
            s += __shfl_xor(s, 8);
            if (lo == 0) red2[r0 + mf * 16 + hi * 4 + rg][cg] = s;
        }
    __syncthreads();
    float lz[2][4];
#pragma unroll
    for (int mf = 0; mf < 2; ++mf)
#pragma unroll
        for (int rg = 0; rg < 4; ++rg) {
            int row = r0 + mf * 16 + hi * 4 + rg;
            const float4* r4 = reinterpret_cast<const float4*>(&red2[row][0]);
            float4 x = r4[0], y = r4[1];
            float s = (x.x + x.y) + (x.z + x.w) + (y.x + y.y) + (y.z + y.w);
            lz[mf][rg] = rmax[mf][rg] + __logf(s);
        }
    float* outbase = out + (size_t)bt * UB * VV;
#pragma unroll
    for (int mf = 0; mf < 2; ++mf)
#pragma unroll
        for (int rg = 0; rg < 4; ++rg) {
            int row = r0 + mf * 16 + hi * 4 + rg;
            float* orow = outbase + (size_t)row * VV + n0 + lo;
#pragma unroll
            for (int nf = 0; nf < 8; ++nf)
                __builtin_nontemporal_store(acc[mf][nf][rg] - lz[mf][rg],
                                            orow + nf * 16);
        }
}

// ---------------------------------------------------------------------------
extern "C" void kernel_launch(void* const* d_in, const int* in_sizes, int n_in,
                              void* d_out, int out_size, void* d_ws, size_t ws_size,
                              hipStream_t stream) {
    const float* enc_in = (const float*)d_in[0];
    const float* dec_in = (const float*)d_in[1];
    const float* We     = (const float*)d_in[2];
    const float* be     = (const float*)d_in[3];
    const float* Wd     = (const float*)d_in[4];
    const float* bd     = (const float*)d_in[5];
    const float* Wo     = (const float*)d_in[6];
    const float* bo     = (const float*)d_in[7];
    float* out = (float*)d_out;

    float* ws   = (float*)d_ws;
    float* encp = ws;                        // 1024*640 f32
    float* decp = ws + 1024 * 640;           // 256*640  f32
    unsigned short* wp = (unsigned short*)(ws + 1024 * 640 + 256 * 640);  // 640*1024 bf16

    kprep<<<520, 256, 0, stream>>>(Wo, wp, enc_in, dec_in, We, be, Wd, bd, encp, decp);
    kmain<<<1024, 1024, 0, stream>>>(encp, decp, wp, bo, out);
}